// Round 1
// baseline (145.601 us; speedup 1.0000x reference)
//
#include <hip/hip_runtime.h>

#define NB 8
#define NS 2048
#define ND 512
#define NKD 64
#define NM (NB*NS)

#define QT 16
#define WIN 144      /* QT + 128 */
#define KP 68        /* padded row stride (floats) for K/V/Q LDS rows */
#define SMEM_FLOATS (3*WIN*KP + 2*QT*KP + QT*WIN)

// ---------------------------------------------------------------------------
// Kernel A: fused projection GEMM.  grid = (NM/128, 5), block = 256.
// p=0: qr=(x@Wqr+b)*scale+pos_qr   p=1: qi likewise
// p=2: kr=x@Wkr+b+pos_kr           p=3: ki likewise        p=4: v=x@Wv+b
// Output: proj[p][m][64] flat in workspace.
// ---------------------------------------------------------------------------
__global__ __launch_bounds__(256) void proj_kernel(
    const float* __restrict__ x,
    const float* __restrict__ w0, const float* __restrict__ w1,
    const float* __restrict__ w2, const float* __restrict__ w3,
    const float* __restrict__ w4,
    const float* __restrict__ b0, const float* __restrict__ b1,
    const float* __restrict__ b2, const float* __restrict__ b3,
    const float* __restrict__ b4,
    const float* __restrict__ p0, const float* __restrict__ p1,
    const float* __restrict__ p2, const float* __restrict__ p3,
    float* __restrict__ o)
{
    const int p = blockIdx.y;
    const float* __restrict__ W    = (p==0)?w0:(p==1)?w1:(p==2)?w2:(p==3)?w3:w4;
    const float* __restrict__ bias = (p==0)?b0:(p==1)?b1:(p==2)?b2:(p==3)?b3:b4;
    const float* __restrict__ pos  = (p==0)?p0:(p==1)?p1:(p==2)?p2:(p==3)?p3:nullptr;

    __shared__ float xs[32][132];   // x tile, transposed: xs[kk][row]
    __shared__ float wt[32][64];    // W tile: wt[kk][col]

    const int tid = threadIdx.x;
    const int tx  = tid & 15;       // col group (4 cols)
    const int ty  = tid >> 4;       // row group (8 rows)
    const int m0  = blockIdx.x * 128;

    float acc[8][4];
    #pragma unroll
    for (int i = 0; i < 8; ++i)
        #pragma unroll
        for (int j = 0; j < 4; ++j) acc[i][j] = 0.f;

    const int xc4 = tid & 7;        // k-chunk (4 of BK=32)
    const int xr  = tid >> 3;       // row 0..31
    const int wc4 = tid & 15;
    const int wr  = tid >> 4;

    for (int k0 = 0; k0 < ND; k0 += 32) {
        #pragma unroll
        for (int pass = 0; pass < 4; ++pass) {
            int row = pass*32 + xr;
            float4 v = *(const float4*)&x[(size_t)(m0+row)*ND + k0 + xc4*4];
            xs[xc4*4+0][row] = v.x;
            xs[xc4*4+1][row] = v.y;
            xs[xc4*4+2][row] = v.z;
            xs[xc4*4+3][row] = v.w;
        }
        #pragma unroll
        for (int pass = 0; pass < 2; ++pass) {
            int kk = pass*16 + wr;
            *(float4*)&wt[kk][wc4*4] =
                *(const float4*)&W[(size_t)(k0+kk)*NKD + wc4*4];
        }
        __syncthreads();
        #pragma unroll
        for (int kk = 0; kk < 32; ++kk) {
            float4 xa = *(const float4*)&xs[kk][ty*8];
            float4 xb = *(const float4*)&xs[kk][ty*8+4];
            float4 wv = *(const float4*)&wt[kk][tx*4];
            float xr8[8] = {xa.x,xa.y,xa.z,xa.w,xb.x,xb.y,xb.z,xb.w};
            float wc[4]  = {wv.x,wv.y,wv.z,wv.w};
            #pragma unroll
            for (int i = 0; i < 8; ++i)
                #pragma unroll
                for (int j = 0; j < 4; ++j)
                    acc[i][j] = fmaf(xr8[i], wc[j], acc[i][j]);
        }
        __syncthreads();
    }

    const float scale = 0.125f;   // 1/sqrt(64)
    #pragma unroll
    for (int i = 0; i < 8; ++i) {
        int m = m0 + ty*8 + i;
        int s = m & (NS-1);
        float v[4];
        #pragma unroll
        for (int j = 0; j < 4; ++j) {
            int c = tx*4 + j;
            float t = acc[i][j] + bias[c];
            if (p < 2)      t = t*scale + pos[s*NKD + c];
            else if (p < 4) t = t + pos[s*NKD + c];
            v[j] = t;
        }
        *(float4*)&o[((size_t)p*NM + m)*NKD + tx*4] =
            make_float4(v[0], v[1], v[2], v[3]);
    }
}

// ---------------------------------------------------------------------------
// Kernel B: banded causal attention.  grid = (NS/QT, NB), block = 256.
// Query tile i0..i0+15; valid keys for query i are j in [i-128, i], i.e.
// local slot jj = j-(i0-128) in [ql, ql+128] (and j >= 0).
// Thread (ql = tid>>4, s = tid&15): 9 key slots jj = s+16m.
// ---------------------------------------------------------------------------
__global__ __launch_bounds__(256) void attn_kernel(
    const float* __restrict__ qkv,
    const float* __restrict__ temp,
    float* __restrict__ out)
{
    extern __shared__ __align__(16) float sm[];
    float* kr_s = sm;                  // WIN*KP
    float* ki_s = kr_s + WIN*KP;
    float* v_s  = ki_s + WIN*KP;
    float* qr_s = v_s  + WIN*KP;       // QT*KP
    float* qi_s = qr_s + QT*KP;
    float* sc   = qi_s + QT*KP;        // QT*WIN  (probs)

    const int tid = threadIdx.x;
    const int i0  = blockIdx.x * QT;
    const int b   = blockIdx.y;
    const int jb  = i0 - 128;          // global j of local slot 0 (may be <0)

    const float* __restrict__ qr_g = qkv + (size_t)0*NM*NKD + (size_t)b*NS*NKD;
    const float* __restrict__ qi_g = qkv + (size_t)1*NM*NKD + (size_t)b*NS*NKD;
    const float* __restrict__ kr_g = qkv + (size_t)2*NM*NKD + (size_t)b*NS*NKD;
    const float* __restrict__ ki_g = qkv + (size_t)3*NM*NKD + (size_t)b*NS*NKD;
    const float* __restrict__ v_g  = qkv + (size_t)4*NM*NKD + (size_t)b*NS*NKD;

    // stage Q tile (16 rows)
    {
        const int row = tid >> 4, c4 = tid & 15;
        *(float4*)&qr_s[row*KP + c4*4] =
            *(const float4*)&qr_g[(size_t)(i0+row)*NKD + c4*4];
        *(float4*)&qi_s[row*KP + c4*4] =
            *(const float4*)&qi_g[(size_t)(i0+row)*NKD + c4*4];
    }
    // stage K/V window (144 rows; zero-fill j<0)
    for (int idx = tid; idx < WIN*16; idx += 256) {
        const int jj = idx >> 4, c4 = idx & 15;
        const int j = jb + jj;
        float4 a = make_float4(0.f,0.f,0.f,0.f), bb = a, cc = a;
        if (j >= 0) {
            a  = *(const float4*)&kr_g[(size_t)j*NKD + c4*4];
            bb = *(const float4*)&ki_g[(size_t)j*NKD + c4*4];
            cc = *(const float4*)&v_g [(size_t)j*NKD + c4*4];
        }
        *(float4*)&kr_s[jj*KP + c4*4] = a;
        *(float4*)&ki_s[jj*KP + c4*4] = bb;
        *(float4*)&v_s [jj*KP + c4*4] = cc;
    }
    __syncthreads();

    const int ql = tid >> 4, s = tid & 15;
    const float T = temp[0];

    // Q row into registers (broadcast LDS reads)
    float4 q_r[16], q_i[16];
    #pragma unroll
    for (int d4 = 0; d4 < 16; ++d4) {
        q_r[d4] = *(const float4*)&qr_s[ql*KP + d4*4];
        q_i[d4] = *(const float4*)&qi_s[ql*KP + d4*4];
    }

    const int lo = (ql > -jb) ? ql : -jb;   // -jb = 128-i0 (j>=0 bound)
    const int hi = ql + 128;

    float scr[9];
    #pragma unroll
    for (int m = 0; m < 9; ++m) {
        const int jj = s + 16*m;
        if (jj >= lo && jj <= hi) {
            float4 ar = make_float4(0.f,0.f,0.f,0.f), ai = ar;
            #pragma unroll
            for (int d4 = 0; d4 < 16; ++d4) {
                float4 kr4 = *(const float4*)&kr_s[jj*KP + d4*4];
                ar.x = fmaf(q_r[d4].x, kr4.x, ar.x);
                ar.y = fmaf(q_r[d4].y, kr4.y, ar.y);
                ar.z = fmaf(q_r[d4].z, kr4.z, ar.z);
                ar.w = fmaf(q_r[d4].w, kr4.w, ar.w);
                float4 ki4 = *(const float4*)&ki_s[jj*KP + d4*4];
                ai.x = fmaf(q_i[d4].x, ki4.x, ai.x);
                ai.y = fmaf(q_i[d4].y, ki4.y, ai.y);
                ai.z = fmaf(q_i[d4].z, ki4.z, ai.z);
                ai.w = fmaf(q_i[d4].w, ki4.w, ai.w);
            }
            float dot = (ar.x+ar.y+ar.z+ar.w) - (ai.x+ai.y+ai.z+ai.w);
            scr[m] = dot * 0.125f * T;
        } else {
            scr[m] = -1e30f;   // exp(-1e30 - mx) underflows to exactly 0
        }
    }

    // softmax across the 16 lanes owning this query
    float mx = scr[0];
    #pragma unroll
    for (int m = 1; m < 9; ++m) mx = fmaxf(mx, scr[m]);
    #pragma unroll
    for (int off = 8; off > 0; off >>= 1)
        mx = fmaxf(mx, __shfl_xor(mx, off, 16));

    float ssum = 0.f;
    #pragma unroll
    for (int m = 0; m < 9; ++m) {
        float e = __expf(scr[m] - mx);
        scr[m] = e;
        ssum += e;
    }
    #pragma unroll
    for (int off = 8; off > 0; off >>= 1)
        ssum += __shfl_xor(ssum, off, 16);
    const float inv = 1.0f / ssum;

    #pragma unroll
    for (int m = 0; m < 9; ++m)
        sc[ql*WIN + s + 16*m] = scr[m] * inv;
    __syncthreads();

    // PV: thread (ql, s) computes out[ql][4s..4s+3]
    const int d0 = s * 4;
    float4 acc = make_float4(0.f,0.f,0.f,0.f);
    for (int jj = 0; jj < WIN; ++jj) {
        const float pv = sc[ql*WIN + jj];
        const float4 v4 = *(const float4*)&v_s[jj*KP + d0];
        acc.x = fmaf(pv, v4.x, acc.x);
        acc.y = fmaf(pv, v4.y, acc.y);
        acc.z = fmaf(pv, v4.z, acc.z);
        acc.w = fmaf(pv, v4.w, acc.w);
    }
    *(float4*)&out[((size_t)b*NS + i0 + ql)*NKD + d0] = acc;
}

// ---------------------------------------------------------------------------
extern "C" void kernel_launch(void* const* d_in, const int* in_sizes, int n_in,
                              void* d_out, int out_size, void* d_ws, size_t ws_size,
                              hipStream_t stream)
{
    const float* x    = (const float*)d_in[0];
    const float* w0   = (const float*)d_in[1];
    const float* b0   = (const float*)d_in[2];
    const float* w1   = (const float*)d_in[3];
    const float* b1   = (const float*)d_in[4];
    const float* w2   = (const float*)d_in[5];
    const float* b2   = (const float*)d_in[6];
    const float* w3   = (const float*)d_in[7];
    const float* b3   = (const float*)d_in[8];
    const float* w4   = (const float*)d_in[9];
    const float* b4   = (const float*)d_in[10];
    const float* p0   = (const float*)d_in[11];
    const float* p1   = (const float*)d_in[12];
    const float* p2   = (const float*)d_in[13];
    const float* p3   = (const float*)d_in[14];
    const float* temp = (const float*)d_in[15];

    float* proj = (float*)d_ws;          // 5 * NM * 64 floats = 20 MB
    float* out  = (float*)d_out;

    dim3 gA(NM/128, 5), blk(256);
    proj_kernel<<<gA, blk, 0, stream>>>(x, w0,w1,w2,w3,w4,
                                        b0,b1,b2,b3,b4,
                                        p0,p1,p2,p3, proj);

    const int smem_bytes = SMEM_FLOATS * (int)sizeof(float);   // 135,424 B
    hipFuncSetAttribute((const void*)attn_kernel,
                        hipFuncAttributeMaxDynamicSharedMemorySize, smem_bytes);
    dim3 gB(NS/QT, NB);
    attn_kernel<<<gB, blk, smem_bytes, stream>>>(proj, temp, out);
}

// Round 2
// 100.198 us; speedup vs baseline: 1.4531x; 1.4531x over previous
//
#include <hip/hip_runtime.h>

#define NB 8
#define NS 2048
#define ND 512
#define NKD 64
#define NM (NB*NS)

#define QT 16
#define WIN 144      /* QT + 128 */
#define KP 68        /* padded row stride (floats) for K/V/Q LDS rows */
#define SMEM_FLOATS (3*WIN*KP + 2*QT*KP + QT*WIN)

typedef _Float16 f16x8 __attribute__((ext_vector_type(8)));
typedef float f32x4 __attribute__((ext_vector_type(4)));

// ---------------------------------------------------------------------------
// Kernel 0: reorder the 5 weight matrices (512x64 f32) into f16 B-fragment
// order for mfma_f32_16x16x32_f16:
//   wfrag[((p*4 + nf)*16 + kt)*64 + lane] = { W[k][n] : n = nf*16 + lane%16,
//                                             k = kt*32 + (lane/16)*8 + j }
// 20480 threads, one f16x8 (16B coalesced) write each.
// ---------------------------------------------------------------------------
__global__ __launch_bounds__(256) void wprep_kernel(
    const float* __restrict__ w0, const float* __restrict__ w1,
    const float* __restrict__ w2, const float* __restrict__ w3,
    const float* __restrict__ w4,
    f16x8* __restrict__ wfrag)
{
    const int t = blockIdx.x * 256 + threadIdx.x;     // 0..20479
    const int p    = t >> 12;
    const int nf   = (t >> 10) & 3;
    const int kt   = (t >> 6) & 15;
    const int lane = t & 63;
    const float* __restrict__ W = (p==0)?w0:(p==1)?w1:(p==2)?w2:(p==3)?w3:w4;
    const int n  = nf*16 + (lane & 15);
    const int k0 = kt*32 + (lane >> 4)*8;
    f16x8 v;
    #pragma unroll
    for (int j = 0; j < 8; ++j)
        v[j] = (_Float16)W[(size_t)(k0 + j)*NKD + n];
    wfrag[t] = v;
}

// ---------------------------------------------------------------------------
// Kernel A: projection GEMM via f16 MFMA, no LDS.
// One wave per (p, 16-row m-tile).  grid = 1280 blocks x 256 thr (4 waves).
// A fragments read x (f32) directly in fragment layout + cvt to f16.
// B fragments are one coalesced 16B/lane load from wfrag.
// Epilogue fuses bias (+ scale + positional for p<4).
// ---------------------------------------------------------------------------
__global__ __launch_bounds__(256) void proj_mfma(
    const float* __restrict__ x,
    const f16x8* __restrict__ wfrag,
    const float* __restrict__ b0, const float* __restrict__ b1,
    const float* __restrict__ b2, const float* __restrict__ b3,
    const float* __restrict__ b4,
    const float* __restrict__ p0, const float* __restrict__ p1,
    const float* __restrict__ p2, const float* __restrict__ p3,
    float* __restrict__ o)
{
    const int g    = (blockIdx.x * 256 + threadIdx.x) >> 6;  // global wave id
    const int lane = threadIdx.x & 63;
    const int p    = g >> 10;          // 0..4
    const int mt   = g & 1023;
    const int m0   = mt * 16;

    const int row = m0 + (lane & 15);
    const int kb  = (lane >> 4) * 8;
    const float* __restrict__ xrow = x + (size_t)row * ND + kb;
    const f16x8* __restrict__ wf   = wfrag + p*4096 + lane;

    f32x4 acc[4];
    #pragma unroll
    for (int nf = 0; nf < 4; ++nf) acc[nf] = (f32x4){0.f,0.f,0.f,0.f};

    for (int kt = 0; kt < 16; ++kt) {
        float4 xa = *(const float4*)(xrow + kt*32);
        float4 xb = *(const float4*)(xrow + kt*32 + 4);
        f16x8 a;
        a[0]=(_Float16)xa.x; a[1]=(_Float16)xa.y;
        a[2]=(_Float16)xa.z; a[3]=(_Float16)xa.w;
        a[4]=(_Float16)xb.x; a[5]=(_Float16)xb.y;
        a[6]=(_Float16)xb.z; a[7]=(_Float16)xb.w;
        #pragma unroll
        for (int nf = 0; nf < 4; ++nf) {
            f16x8 b = wf[nf*1024 + kt*64];
            acc[nf] = __builtin_amdgcn_mfma_f32_16x16x32_f16(a, b, acc[nf], 0, 0, 0);
        }
    }

    const float* __restrict__ bias = (p==0)?b0:(p==1)?b1:(p==2)?b2:(p==3)?b3:b4;
    const float* __restrict__ pos  = (p==0)?p0:(p==1)?p1:(p==2)?p2:(p==3)?p3:nullptr;

    const int col = lane & 15;
    const int r0  = (lane >> 4) << 2;
    float* __restrict__ obase = o + ((size_t)p*NM + m0) * NKD;

    #pragma unroll
    for (int nf = 0; nf < 4; ++nf) {
        const int c = nf*16 + col;
        const float bb = bias[c];
        #pragma unroll
        for (int r = 0; r < 4; ++r) {
            const int mm = r0 + r;
            const int s  = (m0 + mm) & (NS - 1);
            float t = acc[nf][r] + bb;
            if (p < 2)      t = t * 0.125f + pos[s*NKD + c];
            else if (p < 4) t = t + pos[s*NKD + c];
            obase[(size_t)mm*NKD + c] = t;
        }
    }
}

// ---------------------------------------------------------------------------
// Kernel B: banded causal attention (unchanged from round 1).
// ---------------------------------------------------------------------------
__global__ __launch_bounds__(256) void attn_kernel(
    const float* __restrict__ qkv,
    const float* __restrict__ temp,
    float* __restrict__ out)
{
    extern __shared__ __align__(16) float sm[];
    float* kr_s = sm;                  // WIN*KP
    float* ki_s = kr_s + WIN*KP;
    float* v_s  = ki_s + WIN*KP;
    float* qr_s = v_s  + WIN*KP;       // QT*KP
    float* qi_s = qr_s + QT*KP;
    float* sc   = qi_s + QT*KP;        // QT*WIN  (probs)

    const int tid = threadIdx.x;
    const int i0  = blockIdx.x * QT;
    const int b   = blockIdx.y;
    const int jb  = i0 - 128;          // global j of local slot 0 (may be <0)

    const float* __restrict__ qr_g = qkv + (size_t)0*NM*NKD + (size_t)b*NS*NKD;
    const float* __restrict__ qi_g = qkv + (size_t)1*NM*NKD + (size_t)b*NS*NKD;
    const float* __restrict__ kr_g = qkv + (size_t)2*NM*NKD + (size_t)b*NS*NKD;
    const float* __restrict__ ki_g = qkv + (size_t)3*NM*NKD + (size_t)b*NS*NKD;
    const float* __restrict__ v_g  = qkv + (size_t)4*NM*NKD + (size_t)b*NS*NKD;

    // stage Q tile (16 rows)
    {
        const int row = tid >> 4, c4 = tid & 15;
        *(float4*)&qr_s[row*KP + c4*4] =
            *(const float4*)&qr_g[(size_t)(i0+row)*NKD + c4*4];
        *(float4*)&qi_s[row*KP + c4*4] =
            *(const float4*)&qi_g[(size_t)(i0+row)*NKD + c4*4];
    }
    // stage K/V window (144 rows; zero-fill j<0)
    for (int idx = tid; idx < WIN*16; idx += 256) {
        const int jj = idx >> 4, c4 = idx & 15;
        const int j = jb + jj;
        float4 a = make_float4(0.f,0.f,0.f,0.f), bb = a, cc = a;
        if (j >= 0) {
            a  = *(const float4*)&kr_g[(size_t)j*NKD + c4*4];
            bb = *(const float4*)&ki_g[(size_t)j*NKD + c4*4];
            cc = *(const float4*)&v_g [(size_t)j*NKD + c4*4];
        }
        *(float4*)&kr_s[jj*KP + c4*4] = a;
        *(float4*)&ki_s[jj*KP + c4*4] = bb;
        *(float4*)&v_s [jj*KP + c4*4] = cc;
    }
    __syncthreads();

    const int ql = tid >> 4, s = tid & 15;
    const float T = temp[0];

    // Q row into registers (broadcast LDS reads)
    float4 q_r[16], q_i[16];
    #pragma unroll
    for (int d4 = 0; d4 < 16; ++d4) {
        q_r[d4] = *(const float4*)&qr_s[ql*KP + d4*4];
        q_i[d4] = *(const float4*)&qi_s[ql*KP + d4*4];
    }

    const int lo = (ql > -jb) ? ql : -jb;   // -jb = 128-i0 (j>=0 bound)
    const int hi = ql + 128;

    float scr[9];
    #pragma unroll
    for (int m = 0; m < 9; ++m) {
        const int jj = s + 16*m;
        if (jj >= lo && jj <= hi) {
            float4 ar = make_float4(0.f,0.f,0.f,0.f), ai = ar;
            #pragma unroll
            for (int d4 = 0; d4 < 16; ++d4) {
                float4 kr4 = *(const float4*)&kr_s[jj*KP + d4*4];
                ar.x = fmaf(q_r[d4].x, kr4.x, ar.x);
                ar.y = fmaf(q_r[d4].y, kr4.y, ar.y);
                ar.z = fmaf(q_r[d4].z, kr4.z, ar.z);
                ar.w = fmaf(q_r[d4].w, kr4.w, ar.w);
                float4 ki4 = *(const float4*)&ki_s[jj*KP + d4*4];
                ai.x = fmaf(q_i[d4].x, ki4.x, ai.x);
                ai.y = fmaf(q_i[d4].y, ki4.y, ai.y);
                ai.z = fmaf(q_i[d4].z, ki4.z, ai.z);
                ai.w = fmaf(q_i[d4].w, ki4.w, ai.w);
            }
            float dot = (ar.x+ar.y+ar.z+ar.w) - (ai.x+ai.y+ai.z+ai.w);
            scr[m] = dot * 0.125f * T;
        } else {
            scr[m] = -1e30f;   // exp(-1e30 - mx) underflows to exactly 0
        }
    }

    // softmax across the 16 lanes owning this query
    float mx = scr[0];
    #pragma unroll
    for (int m = 1; m < 9; ++m) mx = fmaxf(mx, scr[m]);
    #pragma unroll
    for (int off = 8; off > 0; off >>= 1)
        mx = fmaxf(mx, __shfl_xor(mx, off, 16));

    float ssum = 0.f;
    #pragma unroll
    for (int m = 0; m < 9; ++m) {
        float e = __expf(scr[m] - mx);
        scr[m] = e;
        ssum += e;
    }
    #pragma unroll
    for (int off = 8; off > 0; off >>= 1)
        ssum += __shfl_xor(ssum, off, 16);
    const float inv = 1.0f / ssum;

    #pragma unroll
    for (int m = 0; m < 9; ++m)
        sc[ql*WIN + s + 16*m] = scr[m] * inv;
    __syncthreads();

    // PV: thread (ql, s) computes out[ql][4s..4s+3]
    const int d0 = s * 4;
    float4 acc = make_float4(0.f,0.f,0.f,0.f);
    for (int jj = 0; jj < WIN; ++jj) {
        const float pv = sc[ql*WIN + jj];
        const float4 v4 = *(const float4*)&v_s[jj*KP + d0];
        acc.x = fmaf(pv, v4.x, acc.x);
        acc.y = fmaf(pv, v4.y, acc.y);
        acc.z = fmaf(pv, v4.z, acc.z);
        acc.w = fmaf(pv, v4.w, acc.w);
    }
    *(float4*)&out[((size_t)b*NS + i0 + ql)*NKD + d0] = acc;
}

// ---------------------------------------------------------------------------
extern "C" void kernel_launch(void* const* d_in, const int* in_sizes, int n_in,
                              void* d_out, int out_size, void* d_ws, size_t ws_size,
                              hipStream_t stream)
{
    const float* x    = (const float*)d_in[0];
    const float* w0   = (const float*)d_in[1];
    const float* b0   = (const float*)d_in[2];
    const float* w1   = (const float*)d_in[3];
    const float* b1   = (const float*)d_in[4];
    const float* w2   = (const float*)d_in[5];
    const float* b2   = (const float*)d_in[6];
    const float* w3   = (const float*)d_in[7];
    const float* b3   = (const float*)d_in[8];
    const float* w4   = (const float*)d_in[9];
    const float* b4   = (const float*)d_in[10];
    const float* p0   = (const float*)d_in[11];
    const float* p1   = (const float*)d_in[12];
    const float* p2   = (const float*)d_in[13];
    const float* p3   = (const float*)d_in[14];
    const float* temp = (const float*)d_in[15];

    float* proj  = (float*)d_ws;                          // 5*NM*64 f32 = 20 MB
    f16x8* wfrag = (f16x8*)((char*)d_ws + (size_t)5*NM*NKD*sizeof(float));

    // 0) weight fragment prep: 20480 threads
    wprep_kernel<<<80, 256, 0, stream>>>(w0, w1, w2, w3, w4, wfrag);

    // A) projections: 5120 waves (1024 m-tiles x 5 proj), 4 waves/block
    proj_mfma<<<1280, 256, 0, stream>>>(x, wfrag,
                                        b0, b1, b2, b3, b4,
                                        p0, p1, p2, p3, proj);

    // B) attention
    const int smem_bytes = SMEM_FLOATS * (int)sizeof(float);   // 135,424 B
    hipFuncSetAttribute((const void*)attn_kernel,
                        hipFuncAttributeMaxDynamicSharedMemorySize, smem_bytes);
    dim3 gB(NS/QT, NB);
    attn_kernel<<<gB, 256, smem_bytes, stream>>>(proj, temp, (float*)d_out);
}

// Round 4
// 66.387 us; speedup vs baseline: 2.1932x; 1.5093x over previous
//
#include <hip/hip_runtime.h>

#define NB 8
#define NS 2048
#define ND 512
#define NKD 64
#define NM (NB*NS)

typedef _Float16 f16x8 __attribute__((ext_vector_type(8)));
typedef float f32x4 __attribute__((ext_vector_type(4)));

// ---------------------------------------------------------------------------
// Kernel 0: reorder the 5 weight matrices (512x64 f32) into f16 B-fragment
// order for mfma_f32_16x16x32_f16 (unchanged).
// ---------------------------------------------------------------------------
__global__ __launch_bounds__(256) void wprep_kernel(
    const float* __restrict__ w0, const float* __restrict__ w1,
    const float* __restrict__ w2, const float* __restrict__ w3,
    const float* __restrict__ w4,
    f16x8* __restrict__ wfrag)
{
    const int t = blockIdx.x * 256 + threadIdx.x;     // 0..20479
    const int p    = t >> 12;
    const int nf   = (t >> 10) & 3;
    const int kt   = (t >> 6) & 15;
    const int lane = t & 63;
    const float* __restrict__ W = (p==0)?w0:(p==1)?w1:(p==2)?w2:(p==3)?w3:w4;
    const int n  = nf*16 + (lane & 15);
    const int k0 = kt*32 + (lane >> 4)*8;
    f16x8 v;
    #pragma unroll
    for (int j = 0; j < 8; ++j)
        v[j] = (_Float16)W[(size_t)(k0 + j)*NKD + n];
    wfrag[t] = v;
}

// ---------------------------------------------------------------------------
// Kernel A: projection GEMM via f16 MFMA, no LDS (unchanged).
// ---------------------------------------------------------------------------
__global__ __launch_bounds__(256) void proj_mfma(
    const float* __restrict__ x,
    const f16x8* __restrict__ wfrag,
    const float* __restrict__ b0, const float* __restrict__ b1,
    const float* __restrict__ b2, const float* __restrict__ b3,
    const float* __restrict__ b4,
    const float* __restrict__ p0, const float* __restrict__ p1,
    const float* __restrict__ p2, const float* __restrict__ p3,
    float* __restrict__ o)
{
    const int g    = (blockIdx.x * 256 + threadIdx.x) >> 6;  // global wave id
    const int lane = threadIdx.x & 63;
    const int p    = g >> 10;          // 0..4
    const int mt   = g & 1023;
    const int m0   = mt * 16;

    const int row = m0 + (lane & 15);
    const int kb  = (lane >> 4) * 8;
    const float* __restrict__ xrow = x + (size_t)row * ND + kb;
    const f16x8* __restrict__ wf   = wfrag + p*4096 + lane;

    f32x4 acc[4];
    #pragma unroll
    for (int nf = 0; nf < 4; ++nf) acc[nf] = (f32x4){0.f,0.f,0.f,0.f};

    for (int kt = 0; kt < 16; ++kt) {
        float4 xa = *(const float4*)(xrow + kt*32);
        float4 xb = *(const float4*)(xrow + kt*32 + 4);
        f16x8 a;
        a[0]=(_Float16)xa.x; a[1]=(_Float16)xa.y;
        a[2]=(_Float16)xa.z; a[3]=(_Float16)xa.w;
        a[4]=(_Float16)xb.x; a[5]=(_Float16)xb.y;
        a[6]=(_Float16)xb.z; a[7]=(_Float16)xb.w;
        #pragma unroll
        for (int nf = 0; nf < 4; ++nf) {
            f16x8 b = wf[nf*1024 + kt*64];
            acc[nf] = __builtin_amdgcn_mfma_f32_16x16x32_f16(a, b, acc[nf], 0, 0, 0);
        }
    }

    const float* __restrict__ bias = (p==0)?b0:(p==1)?b1:(p==2)?b2:(p==3)?b3:b4;
    const float* __restrict__ pos  = (p==0)?p0:(p==1)?p1:(p==2)?p2:(p==3)?p3:nullptr;

    const int col = lane & 15;
    const int r0  = (lane >> 4) << 2;
    float* __restrict__ obase = o + ((size_t)p*NM + m0) * NKD;

    #pragma unroll
    for (int nf = 0; nf < 4; ++nf) {
        const int c = nf*16 + col;
        const float bb = bias[c];
        #pragma unroll
        for (int r = 0; r < 4; ++r) {
            const int mm = r0 + r;
            const int s  = (m0 + mm) & (NS - 1);
            float t = acc[nf][r] + bb;
            if (p < 2)      t = t * 0.125f + pos[s*NKD + c];
            else if (p < 4) t = t + pos[s*NKD + c];
            obase[(size_t)mm*NKD + c] = t;
        }
    }
}

// ---------------------------------------------------------------------------
// Kernel B: banded causal attention via f16 MFMA.
// Identical to round 3 EXCEPT the K-staging index split (the bug):
// per-matrix item count is NT*2*64 = 1536, not 2048.
// ---------------------------------------------------------------------------
#define QB 64
#define NT 12                 /* 16-key tiles in window (window = 192 keys) */
#define KITEMS (NT*2*64)      /* 1536 f16x8 fragment items per K matrix */
#define PSTR 200              /* f16 stride for P rows */
#define ATTN_LDS (3*NT*2*64*16 + 4*16*PSTR*2)   /* 73728 + 25600 = 99328 B */

__global__ __launch_bounds__(256) void attn_mfma(
    const float* __restrict__ qkv,
    const float* __restrict__ temp,
    float* __restrict__ out)
{
    extern __shared__ __align__(16) char smem[];
    _Float16* krf = (_Float16*)smem;            // [tile][kt][lane] f16x8
    _Float16* kif = krf + KITEMS*8;
    _Float16* vf  = kif + KITEMS*8;             // [kt(6)][nf(4)][lane] f16x8
    _Float16* pl  = vf  + 6*4*64*8;             // [wave][16][PSTR] f16

    const int tid  = threadIdx.x;
    const int w    = tid >> 6;
    const int lane = tid & 63;
    const int i0   = blockIdx.x * QB;
    const int b    = blockIdx.y;
    const int jb   = i0 - 128;                  // global key of window slot 0

    const float* __restrict__ qr_g = qkv + ((size_t)0*NM + (size_t)b*NS)*NKD;
    const float* __restrict__ qi_g = qkv + ((size_t)1*NM + (size_t)b*NS)*NKD;
    const float* __restrict__ kr_g = qkv + ((size_t)2*NM + (size_t)b*NS)*NKD;
    const float* __restrict__ ki_g = qkv + ((size_t)3*NM + (size_t)b*NS)*NKD;
    const float* __restrict__ v_g  = qkv + ((size_t)4*NM + (size_t)b*NS)*NKD;

    // ---- stage K fragments (kr, ki): 2 * KITEMS items ----  [BUGFIX]
    for (int it = tid; it < 2*KITEMS; it += 256) {
        const int mtx = (it >= KITEMS) ? 1 : 0;
        const int r   = it - mtx*KITEMS;        // 0..1535
        const int t   = r >> 7;
        const int kt  = (r >> 6) & 1;
        const int ln  = r & 63;
        const int row = jb + 16*t + (ln & 15);
        const int d0  = kt*32 + (ln >> 4)*8;
        f16x8 v = {};
        if (row >= 0) {
            const float* src = (mtx ? ki_g : kr_g) + (size_t)row*NKD + d0;
            float4 a = *(const float4*)src;
            float4 c = *(const float4*)(src + 4);
            v[0]=(_Float16)a.x; v[1]=(_Float16)a.y;
            v[2]=(_Float16)a.z; v[3]=(_Float16)a.w;
            v[4]=(_Float16)c.x; v[5]=(_Float16)c.y;
            v[6]=(_Float16)c.z; v[7]=(_Float16)c.w;
        }
        ((f16x8*)(mtx ? kif : krf))[r] = v;
    }
    // ---- stage V fragments (B-layout: n=d, k=key): 6*4*64 items ----
    for (int it = tid; it < 6*4*64; it += 256) {
        const int kt = it >> 8;
        const int nf = (it >> 6) & 3;
        const int ln = it & 63;
        const int d  = nf*16 + (ln & 15);
        const int k0 = jb + kt*32 + (ln >> 4)*8;
        f16x8 v = {};
        #pragma unroll
        for (int j = 0; j < 8; ++j)
            if (k0 + j >= 0) v[j] = (_Float16)v_g[(size_t)(k0+j)*NKD + d];
        ((f16x8*)vf)[it] = v;
    }

    // ---- Q fragments in registers (imag part negated: qr·kr − qi·ki) ----
    const int qrow = i0 + 16*w + (lane & 15);
    const int d0   = (lane >> 4)*8;
    f16x8 aqr[2], aqi[2];
    #pragma unroll
    for (int kt = 0; kt < 2; ++kt) {
        const float* sr = qr_g + (size_t)qrow*NKD + kt*32 + d0;
        const float* si = qi_g + (size_t)qrow*NKD + kt*32 + d0;
        float4 a = *(const float4*)sr, c = *(const float4*)(sr+4);
        float4 e = *(const float4*)si, f = *(const float4*)(si+4);
        aqr[kt][0]=(_Float16)a.x;  aqr[kt][1]=(_Float16)a.y;
        aqr[kt][2]=(_Float16)a.z;  aqr[kt][3]=(_Float16)a.w;
        aqr[kt][4]=(_Float16)c.x;  aqr[kt][5]=(_Float16)c.y;
        aqr[kt][6]=(_Float16)c.z;  aqr[kt][7]=(_Float16)c.w;
        aqi[kt][0]=(_Float16)-e.x; aqi[kt][1]=(_Float16)-e.y;
        aqi[kt][2]=(_Float16)-e.z; aqi[kt][3]=(_Float16)-e.w;
        aqi[kt][4]=(_Float16)-f.x; aqi[kt][5]=(_Float16)-f.y;
        aqi[kt][6]=(_Float16)-f.z; aqi[kt][7]=(_Float16)-f.w;
    }
    __syncthreads();

    // ---- QK^T: 9 tiles x 4 MFMA ----
    f32x4 st[9];
    #pragma unroll
    for (int t = 0; t < 9; ++t) {
        const int tt = w + t;
        f32x4 acc = (f32x4){0.f,0.f,0.f,0.f};
        acc = __builtin_amdgcn_mfma_f32_16x16x32_f16(aqr[0], ((f16x8*)krf)[(tt*2+0)*64+lane], acc, 0,0,0);
        acc = __builtin_amdgcn_mfma_f32_16x16x32_f16(aqr[1], ((f16x8*)krf)[(tt*2+1)*64+lane], acc, 0,0,0);
        acc = __builtin_amdgcn_mfma_f32_16x16x32_f16(aqi[0], ((f16x8*)kif)[(tt*2+0)*64+lane], acc, 0,0,0);
        acc = __builtin_amdgcn_mfma_f32_16x16x32_f16(aqi[1], ((f16x8*)kif)[(tt*2+1)*64+lane], acc, 0,0,0);
        st[t] = acc;
    }

    // ---- mask + scale, row-max/sum (regs + shfl over the 16 col-lanes) ----
    const float sT  = 0.125f * temp[0];
    const int col   = lane & 15;
    const int qg4   = (lane >> 4) * 4;
    const int jrmin = -jb;                      // j_global >= 0
    float mx[4] = {-3e38f, -3e38f, -3e38f, -3e38f};
    #pragma unroll
    for (int t = 0; t < 9; ++t) {
        const int jr = 16*(w + t) + col;
        #pragma unroll
        for (int r = 0; r < 4; ++r) {
            const int row16 = 16*w + qg4 + r;   // valid jj: [row16, row16+128]
            const bool ok = (jr >= row16) && (jr <= 128 + row16) && (jr >= jrmin);
            const float s = ok ? st[t][r]*sT : -1e30f;
            st[t][r] = s;
            mx[r] = fmaxf(mx[r], s);
        }
    }
    #pragma unroll
    for (int off = 1; off < 16; off <<= 1)
        #pragma unroll
        for (int r = 0; r < 4; ++r)
            mx[r] = fmaxf(mx[r], __shfl_xor(mx[r], off, 16));

    float sum[4] = {0.f, 0.f, 0.f, 0.f};
    #pragma unroll
    for (int t = 0; t < 9; ++t)
        #pragma unroll
        for (int r = 0; r < 4; ++r) {
            const float e = __expf(st[t][r] - mx[r]);
            st[t][r] = e;
            sum[r] += e;
        }
    #pragma unroll
    for (int off = 1; off < 16; off <<= 1)
        #pragma unroll
        for (int r = 0; r < 4; ++r)
            sum[r] += __shfl_xor(sum[r], off, 16);
    float inv[4];
    #pragma unroll
    for (int r = 0; r < 4; ++r) inv[r] = 1.0f / sum[r];

    // ---- write P (f16) to per-wave LDS in A-frag layout ----
    _Float16* plw = pl + w*16*PSTR;
    #pragma unroll
    for (int t = 0; t < 9; ++t) {
        const int jr = 16*(w + t) + col;
        #pragma unroll
        for (int r = 0; r < 4; ++r)
            plw[(qg4 + r)*PSTR + jr] = (_Float16)(st[t][r] * inv[r]);
    }
    // zero the one covered-but-uncomputed boundary tile
    {
        const int tz = (w & 1) ? (w - 1) : (w + 9);
        #pragma unroll
        for (int r = 0; r < 4; ++r)
            plw[(qg4 + r)*PSTR + 16*tz + col] = (_Float16)0.f;
    }
    __syncthreads();

    // ---- PV: 5 k-steps x 4 n-tiles ----
    f32x4 oacc[4];
    #pragma unroll
    for (int nf = 0; nf < 4; ++nf) oacc[nf] = (f32x4){0.f,0.f,0.f,0.f};
    const int ktlo = w >> 1;
    const _Float16* pa = plw + (lane & 15)*PSTR + (lane >> 4)*8;
    #pragma unroll
    for (int kk = 0; kk < 5; ++kk) {
        const int kt = ktlo + kk;
        f16x8 a = *(const f16x8*)(pa + kt*32);
        #pragma unroll
        for (int nf = 0; nf < 4; ++nf)
            oacc[nf] = __builtin_amdgcn_mfma_f32_16x16x32_f16(
                a, ((f16x8*)vf)[(kt*4+nf)*64+lane], oacc[nf], 0,0,0);
    }

    // ---- epilogue ----
    float* ob = out + ((size_t)b*NS + i0 + 16*w)*NKD;
    #pragma unroll
    for (int nf = 0; nf < 4; ++nf)
        #pragma unroll
        for (int r = 0; r < 4; ++r)
            ob[(size_t)(qg4 + r)*NKD + nf*16 + col] = oacc[nf][r];
}

// ---------------------------------------------------------------------------
extern "C" void kernel_launch(void* const* d_in, const int* in_sizes, int n_in,
                              void* d_out, int out_size, void* d_ws, size_t ws_size,
                              hipStream_t stream)
{
    const float* x    = (const float*)d_in[0];
    const float* w0   = (const float*)d_in[1];
    const float* b0   = (const float*)d_in[2];
    const float* w1   = (const float*)d_in[3];
    const float* b1   = (const float*)d_in[4];
    const float* w2   = (const float*)d_in[5];
    const float* b2   = (const float*)d_in[6];
    const float* w3   = (const float*)d_in[7];
    const float* b3   = (const float*)d_in[8];
    const float* w4   = (const float*)d_in[9];
    const float* b4   = (const float*)d_in[10];
    const float* p0   = (const float*)d_in[11];
    const float* p1   = (const float*)d_in[12];
    const float* p2   = (const float*)d_in[13];
    const float* p3   = (const float*)d_in[14];
    const float* temp = (const float*)d_in[15];

    float* proj  = (float*)d_ws;                          // 5*NM*64 f32 = 20 MB
    f16x8* wfrag = (f16x8*)((char*)d_ws + (size_t)5*NM*NKD*sizeof(float));

    wprep_kernel<<<80, 256, 0, stream>>>(w0, w1, w2, w3, w4, wfrag);

    proj_mfma<<<1280, 256, 0, stream>>>(x, wfrag,
                                        b0, b1, b2, b3, b4,
                                        p0, p1, p2, p3, proj);

    hipFuncSetAttribute((const void*)attn_mfma,
                        hipFuncAttributeMaxDynamicSharedMemorySize, ATTN_LDS);
    dim3 gB(NS/QB, NB);
    attn_mfma<<<gB, 256, ATTN_LDS, stream>>>(proj, temp, (float*)d_out);
}

// Round 5
// 42.297 us; speedup vs baseline: 3.4423x; 1.5695x over previous
//
#include <hip/hip_runtime.h>

#define NB 8
#define NS 2048
#define ND 512
#define NKD 64
#define NM (NB*NS)

typedef _Float16 f16x8 __attribute__((ext_vector_type(8)));
typedef float f32x4 __attribute__((ext_vector_type(4)));

// ---------------------------------------------------------------------------
// Workspace layout (f16):
//   wfrag : 20480 f16x8 (327,680 B)  -- W B-fragments, 5 projections
//   qkri  : [p in 0..3][m in 0..NM)[64] f16   (8,388,608 B)  p: qr,qi,kr,ki
//   vT    : [b][d in 0..64)[s in 0..NS) f16   (2,097,152 B)  transposed V
// ---------------------------------------------------------------------------

// Kernel 0: W -> f16 B-fragment order for mfma_f32_16x16x32_f16 (unchanged).
__global__ __launch_bounds__(256) void wprep_kernel(
    const float* __restrict__ w0, const float* __restrict__ w1,
    const float* __restrict__ w2, const float* __restrict__ w3,
    const float* __restrict__ w4,
    f16x8* __restrict__ wfrag)
{
    const int t = blockIdx.x * 256 + threadIdx.x;     // 0..20479
    const int p    = t >> 12;
    const int nf   = (t >> 10) & 3;
    const int kt   = (t >> 6) & 15;
    const int lane = t & 63;
    const float* __restrict__ W = (p==0)?w0:(p==1)?w1:(p==2)?w2:(p==3)?w3:w4;
    const int n  = nf*16 + (lane & 15);
    const int k0 = kt*32 + (lane >> 4)*8;
    f16x8 v;
    #pragma unroll
    for (int j = 0; j < 8; ++j)
        v[j] = (_Float16)W[(size_t)(k0 + j)*NKD + n];
    wfrag[t] = v;
}

// ---------------------------------------------------------------------------
// Kernel A: FUSED projection GEMM — one wave computes ALL 5 projections for a
// 16-row m-tile (x read once).  grid = 256 blocks x 256 thr (1024 waves).
// Outputs f16: qr/qi/kr/ki row-major [p][m][64]; V transposed vT[b][d][s].
// ---------------------------------------------------------------------------
__global__ __launch_bounds__(256) void proj_mfma(
    const float* __restrict__ x,
    const f16x8* __restrict__ wfrag,
    const float* __restrict__ b0, const float* __restrict__ b1,
    const float* __restrict__ b2, const float* __restrict__ b3,
    const float* __restrict__ b4,
    const float* __restrict__ p0, const float* __restrict__ p1,
    const float* __restrict__ p2, const float* __restrict__ p3,
    _Float16* __restrict__ qkri,
    _Float16* __restrict__ vT)
{
    const int g    = (blockIdx.x * 256 + threadIdx.x) >> 6;  // m-tile 0..1023
    const int lane = threadIdx.x & 63;
    const int m0   = g * 16;

    const int row = m0 + (lane & 15);
    const int kb  = (lane >> 4) * 8;
    const float* __restrict__ xrow = x + (size_t)row * ND + kb;
    const f16x8* __restrict__ wf   = wfrag + lane;

    f32x4 acc[5][4];
    #pragma unroll
    for (int p = 0; p < 5; ++p)
        #pragma unroll
        for (int nf = 0; nf < 4; ++nf) acc[p][nf] = (f32x4){0.f,0.f,0.f,0.f};

    for (int kt = 0; kt < 16; ++kt) {
        float4 xa = *(const float4*)(xrow + kt*32);
        float4 xb = *(const float4*)(xrow + kt*32 + 4);
        f16x8 a;
        a[0]=(_Float16)xa.x; a[1]=(_Float16)xa.y;
        a[2]=(_Float16)xa.z; a[3]=(_Float16)xa.w;
        a[4]=(_Float16)xb.x; a[5]=(_Float16)xb.y;
        a[6]=(_Float16)xb.z; a[7]=(_Float16)xb.w;
        #pragma unroll
        for (int p = 0; p < 5; ++p)
            #pragma unroll
            for (int nf = 0; nf < 4; ++nf) {
                f16x8 b = wf[(p*4 + nf)*1024 + kt*64];
                acc[p][nf] = __builtin_amdgcn_mfma_f32_16x16x32_f16(a, b, acc[p][nf], 0, 0, 0);
            }
    }

    const float* biases[5] = {b0, b1, b2, b3, b4};
    const float* poss[4]   = {p0, p1, p2, p3};

    const int col   = lane & 15;
    const int rbase = (lane >> 4) << 2;
    const int bidx  = m0 >> 11;               // batch (tile never crosses)

    // qr, qi, kr, ki -> qkri[p][m][64] f16
    #pragma unroll
    for (int p = 0; p < 4; ++p) {
        _Float16* ob = qkri + ((size_t)p*NM + m0) * NKD;
        #pragma unroll
        for (int nf = 0; nf < 4; ++nf) {
            const int c = nf*16 + col;
            const float bb = biases[p][c];
            #pragma unroll
            for (int r = 0; r < 4; ++r) {
                const int mm = rbase + r;
                const int s  = (m0 + mm) & (NS - 1);
                float t = acc[p][nf][r] + bb;
                if (p < 2) t = t * 0.125f + poss[p][s*NKD + c];
                else       t = t + poss[p][s*NKD + c];
                ob[(size_t)mm*NKD + c] = (_Float16)t;
            }
        }
    }
    // v -> vT[b][d][s] f16
    {
        _Float16* vb = vT + (size_t)bidx*NKD*NS;
        #pragma unroll
        for (int nf = 0; nf < 4; ++nf) {
            const int c = nf*16 + col;
            const float bb = b4[c];
            #pragma unroll
            for (int r = 0; r < 4; ++r) {
                const int s = (m0 + rbase + r) & (NS - 1);
                vb[(size_t)c*NS + s] = (_Float16)(acc[4][nf][r] + bb);
            }
        }
    }
}

// ---------------------------------------------------------------------------
// Kernel B: banded causal attention via f16 MFMA.  Staging is now pure 16B
// f16x8 copies (no converts, no gathers): K/Q from qkri, V from vT.
// Structure otherwise identical to round 4 (which passed).
// ---------------------------------------------------------------------------
#define QB 64
#define NT 12                 /* 16-key tiles in window (window = 192 keys) */
#define KITEMS (NT*2*64)      /* 1536 f16x8 fragment items per K matrix */
#define PSTR 200              /* f16 stride for P rows */
#define ATTN_LDS (3*NT*2*64*16 + 4*16*PSTR*2)   /* 73728 + 25600 = 99328 B */

__global__ __launch_bounds__(256) void attn_mfma(
    const _Float16* __restrict__ qkri,
    const _Float16* __restrict__ vT,
    const float* __restrict__ temp,
    float* __restrict__ out)
{
    extern __shared__ __align__(16) char smem[];
    _Float16* krf = (_Float16*)smem;            // [tile][kt][lane] f16x8
    _Float16* kif = krf + KITEMS*8;
    _Float16* vf  = kif + KITEMS*8;             // [kt(6)][nf(4)][lane] f16x8
    _Float16* pl  = vf  + 6*4*64*8;             // [wave][16][PSTR] f16

    const int tid  = threadIdx.x;
    const int w    = tid >> 6;
    const int lane = tid & 63;
    const int i0   = blockIdx.x * QB;
    const int b    = blockIdx.y;
    const int jb   = i0 - 128;                  // global key of window slot 0

    const _Float16* __restrict__ qr_g = qkri + ((size_t)0*NM + (size_t)b*NS)*NKD;
    const _Float16* __restrict__ qi_g = qkri + ((size_t)1*NM + (size_t)b*NS)*NKD;
    const _Float16* __restrict__ kr_g = qkri + ((size_t)2*NM + (size_t)b*NS)*NKD;
    const _Float16* __restrict__ ki_g = qkri + ((size_t)3*NM + (size_t)b*NS)*NKD;
    const _Float16* __restrict__ vT_b = vT + (size_t)b*NKD*NS;

    // ---- stage K fragments (kr, ki): 2*KITEMS 16B copies ----
    for (int it = tid; it < 2*KITEMS; it += 256) {
        const int mtx = (it >= KITEMS) ? 1 : 0;
        const int r   = it - mtx*KITEMS;        // 0..1535
        const int t   = r >> 7;
        const int kt  = (r >> 6) & 1;
        const int ln  = r & 63;
        const int row = jb + 16*t + (ln & 15);
        const int d0  = kt*32 + (ln >> 4)*8;
        f16x8 v = {};
        if (row >= 0)
            v = *(const f16x8*)&(mtx ? ki_g : kr_g)[(size_t)row*NKD + d0];
        ((f16x8*)(mtx ? kif : krf))[r] = v;
    }
    // ---- stage V fragments: contiguous 16B loads from vT ----
    for (int it = tid; it < 6*4*64; it += 256) {
        const int kt = it >> 8;
        const int nf = (it >> 6) & 3;
        const int ln = it & 63;
        const int d  = nf*16 + (ln & 15);
        const int k0 = jb + kt*32 + (ln >> 4)*8;   // multiple of 8
        f16x8 v = {};
        if (k0 >= 0)
            v = *(const f16x8*)&vT_b[(size_t)d*NS + k0];
        ((f16x8*)vf)[it] = v;
    }

    // ---- Q fragments in registers (imag negated: qr·kr − qi·ki) ----
    const int qrow = i0 + 16*w + (lane & 15);
    const int d0   = (lane >> 4)*8;
    f16x8 aqr[2], aqi[2];
    #pragma unroll
    for (int kt = 0; kt < 2; ++kt) {
        aqr[kt] = *(const f16x8*)&qr_g[(size_t)qrow*NKD + kt*32 + d0];
        f16x8 qi8 = *(const f16x8*)&qi_g[(size_t)qrow*NKD + kt*32 + d0];
        aqi[kt] = -qi8;
    }
    __syncthreads();

    // ---- QK^T: 9 tiles x 4 MFMA ----
    f32x4 st[9];
    #pragma unroll
    for (int t = 0; t < 9; ++t) {
        const int tt = w + t;
        f32x4 acc = (f32x4){0.f,0.f,0.f,0.f};
        acc = __builtin_amdgcn_mfma_f32_16x16x32_f16(aqr[0], ((f16x8*)krf)[(tt*2+0)*64+lane], acc, 0,0,0);
        acc = __builtin_amdgcn_mfma_f32_16x16x32_f16(aqr[1], ((f16x8*)krf)[(tt*2+1)*64+lane], acc, 0,0,0);
        acc = __builtin_amdgcn_mfma_f32_16x16x32_f16(aqi[0], ((f16x8*)kif)[(tt*2+0)*64+lane], acc, 0,0,0);
        acc = __builtin_amdgcn_mfma_f32_16x16x32_f16(aqi[1], ((f16x8*)kif)[(tt*2+1)*64+lane], acc, 0,0,0);
        st[t] = acc;
    }

    // ---- mask + scale, row max/sum over the 16 col-lanes ----
    const float sT  = 0.125f * temp[0];
    const int col   = lane & 15;
    const int qg4   = (lane >> 4) * 4;
    const int jrmin = -jb;                      // j_global >= 0
    float mx[4] = {-3e38f, -3e38f, -3e38f, -3e38f};
    #pragma unroll
    for (int t = 0; t < 9; ++t) {
        const int jr = 16*(w + t) + col;
        #pragma unroll
        for (int r = 0; r < 4; ++r) {
            const int row16 = 16*w + qg4 + r;   // valid jj: [row16, row16+128]
            const bool ok = (jr >= row16) && (jr <= 128 + row16) && (jr >= jrmin);
            const float s = ok ? st[t][r]*sT : -1e30f;
            st[t][r] = s;
            mx[r] = fmaxf(mx[r], s);
        }
    }
    #pragma unroll
    for (int off = 1; off < 16; off <<= 1)
        #pragma unroll
        for (int r = 0; r < 4; ++r)
            mx[r] = fmaxf(mx[r], __shfl_xor(mx[r], off, 16));

    float sum[4] = {0.f, 0.f, 0.f, 0.f};
    #pragma unroll
    for (int t = 0; t < 9; ++t)
        #pragma unroll
        for (int r = 0; r < 4; ++r) {
            const float e = __expf(st[t][r] - mx[r]);
            st[t][r] = e;
            sum[r] += e;
        }
    #pragma unroll
    for (int off = 1; off < 16; off <<= 1)
        #pragma unroll
        for (int r = 0; r < 4; ++r)
            sum[r] += __shfl_xor(sum[r], off, 16);
    float inv[4];
    #pragma unroll
    for (int r = 0; r < 4; ++r) inv[r] = 1.0f / sum[r];

    // ---- write P (f16) to per-wave LDS in A-frag layout ----
    _Float16* plw = pl + w*16*PSTR;
    #pragma unroll
    for (int t = 0; t < 9; ++t) {
        const int jr = 16*(w + t) + col;
        #pragma unroll
        for (int r = 0; r < 4; ++r)
            plw[(qg4 + r)*PSTR + jr] = (_Float16)(st[t][r] * inv[r]);
    }
    {   // zero the covered-but-uncomputed boundary tile
        const int tz = (w & 1) ? (w - 1) : (w + 9);
        #pragma unroll
        for (int r = 0; r < 4; ++r)
            plw[(qg4 + r)*PSTR + 16*tz + col] = (_Float16)0.f;
    }
    __syncthreads();

    // ---- PV: 5 k-steps x 4 n-tiles ----
    f32x4 oacc[4];
    #pragma unroll
    for (int nf = 0; nf < 4; ++nf) oacc[nf] = (f32x4){0.f,0.f,0.f,0.f};
    const int ktlo = w >> 1;
    const _Float16* pa = plw + (lane & 15)*PSTR + (lane >> 4)*8;
    #pragma unroll
    for (int kk = 0; kk < 5; ++kk) {
        const int kt = ktlo + kk;
        f16x8 a = *(const f16x8*)(pa + kt*32);
        #pragma unroll
        for (int nf = 0; nf < 4; ++nf)
            oacc[nf] = __builtin_amdgcn_mfma_f32_16x16x32_f16(
                a, ((f16x8*)vf)[(kt*4+nf)*64+lane], oacc[nf], 0,0,0);
    }

    // ---- epilogue ----
    float* ob = out + ((size_t)b*NS + i0 + 16*w)*NKD;
    #pragma unroll
    for (int nf = 0; nf < 4; ++nf)
        #pragma unroll
        for (int r = 0; r < 4; ++r)
            ob[(size_t)(qg4 + r)*NKD + nf*16 + col] = oacc[nf][r];
}

// ---------------------------------------------------------------------------
extern "C" void kernel_launch(void* const* d_in, const int* in_sizes, int n_in,
                              void* d_out, int out_size, void* d_ws, size_t ws_size,
                              hipStream_t stream)
{
    const float* x    = (const float*)d_in[0];
    const float* w0   = (const float*)d_in[1];
    const float* b0   = (const float*)d_in[2];
    const float* w1   = (const float*)d_in[3];
    const float* b1   = (const float*)d_in[4];
    const float* w2   = (const float*)d_in[5];
    const float* b2   = (const float*)d_in[6];
    const float* w3   = (const float*)d_in[7];
    const float* b3   = (const float*)d_in[8];
    const float* w4   = (const float*)d_in[9];
    const float* b4   = (const float*)d_in[10];
    const float* p0   = (const float*)d_in[11];
    const float* p1   = (const float*)d_in[12];
    const float* p2   = (const float*)d_in[13];
    const float* p3   = (const float*)d_in[14];
    const float* temp = (const float*)d_in[15];

    char* ws = (char*)d_ws;
    f16x8*    wfrag = (f16x8*)ws;                              // 327,680 B
    _Float16* qkri  = (_Float16*)(ws + 327680);                // 8,388,608 B
    _Float16* vT    = (_Float16*)(ws + 327680 + 8388608);      // 2,097,152 B

    wprep_kernel<<<80, 256, 0, stream>>>(w0, w1, w2, w3, w4, wfrag);

    proj_mfma<<<256, 256, 0, stream>>>(x, wfrag,
                                       b0, b1, b2, b3, b4,
                                       p0, p1, p2, p3, qkri, vT);

    hipFuncSetAttribute((const void*)attn_mfma,
                        hipFuncAttributeMaxDynamicSharedMemorySize, ATTN_LDS);
    dim3 gB(NS/QB, NB);
    attn_mfma<<<gB, 256, ATTN_LDS, stream>>>(qkri, vT, temp, (float*)d_out);
}